// Round 1
// baseline (714.334 us; speedup 1.0000x reference)
//
#include <hip/hip_runtime.h>

// VectorQuantizer on MI355X.
// z: [64,1024,256] f32 -> N=65536 rows, D=256. codebook: [1024,256] f32, K=1024.
// Outputs (concat flat): z_q (16777216 f32), loss (1), perplexity (1).

#define N_ROWS 65536
#define DIM    256
#define K_CODES 1024
#define BM     32      // rows per block
#define CHUNK  512     // codes per outer chunk
#define DSTAGE 16      // d-slice per cs stage
#define CS_PAD 20      // padded float stride per code row in LDS (16 + 4, keeps 16B align)
#define BETA   0.001f
#define NBLOCKS (N_ROWS / BM)   // 2048

// ws layout (floats):
// [0,1024)     cnorm
// [1024,2048)  counts (int, atomics; zeroed each launch)
// [2048,4096)  per-block partial loss (NBLOCKS floats)

__global__ void cnorm_kernel(const float* __restrict__ cb, float* __restrict__ cnorm) {
    int k = blockIdx.x * blockDim.x + threadIdx.x;
    if (k >= K_CODES) return;
    const float4* row = (const float4*)(cb + (size_t)k * DIM);
    float s = 0.f;
#pragma unroll
    for (int j = 0; j < DIM / 4; ++j) {
        float4 v = row[j];
        s = fmaf(v.x, v.x, s);
        s = fmaf(v.y, v.y, s);
        s = fmaf(v.z, v.z, s);
        s = fmaf(v.w, v.w, s);
    }
    cnorm[k] = s;
}

__global__ __launch_bounds__(256, 2)
void vq_main(const float* __restrict__ z, const float* __restrict__ cb,
             const float* __restrict__ cnorm, float* __restrict__ out,
             int* __restrict__ counts, float* __restrict__ ploss) {
    __shared__ float zs[BM][DIM];          // 32 KB, rows broadcast-read
    __shared__ float cs[CHUNK][CS_PAD];    // 40 KB
    __shared__ int   bests[BM];
    __shared__ float red[256];

    const int tid = threadIdx.x;
    const int tx  = tid & 63;    // lane
    const int ty  = tid >> 6;    // wave id 0..3 -> row group of 8
    const int r0  = blockIdx.x * BM;

    // ---- stage z tile (coalesced float4) ----
    {
        const float4* zg  = (const float4*)(z + (size_t)r0 * DIM);
        float4*       zsv = (float4*)&zs[0][0];
#pragma unroll
        for (int j = 0; j < (BM * DIM / 4) / 256; ++j)
            zsv[tid + 256 * j] = zg[tid + 256 * j];
    }

    unsigned long long best[8];
#pragma unroll
    for (int i = 0; i < 8; ++i) best[i] = ~0ull;

    for (int cb0 = 0; cb0 < K_CODES; cb0 += CHUNK) {
        float acc[8][8];
#pragma unroll
        for (int i = 0; i < 8; ++i)
#pragma unroll
            for (int m = 0; m < 8; ++m) acc[i][m] = 0.f;

        for (int sd = 0; sd < DIM / DSTAGE; ++sd) {
            __syncthreads();   // protect cs from previous stage's readers
            // stage cs: CHUNK codes x DSTAGE floats = 2048 float4
#pragma unroll
            for (int j = 0; j < 8; ++j) {
                int f4i = tid + 256 * j;
                int c   = f4i >> 2;
                int q   = f4i & 3;
                float4 v = *(const float4*)(cb + (size_t)(cb0 + c) * DIM + sd * DSTAGE + q * 4);
                *(float4*)&cs[c][q * 4] = v;
            }
            __syncthreads();

#pragma unroll
            for (int dd4 = 0; dd4 < DSTAGE / 4; ++dd4) {
                float4 zv[8], cv[8];
#pragma unroll
                for (int i = 0; i < 8; ++i)
                    zv[i] = *(const float4*)&zs[ty * 8 + i][sd * DSTAGE + dd4 * 4];
#pragma unroll
                for (int m = 0; m < 8; ++m)
                    cv[m] = *(const float4*)&cs[tx + 64 * m][dd4 * 4];
#pragma unroll
                for (int i = 0; i < 8; ++i) {
#pragma unroll
                    for (int m = 0; m < 8; ++m) {
                        float a = acc[i][m];
                        a = fmaf(zv[i].x, cv[m].x, a);
                        a = fmaf(zv[i].y, cv[m].y, a);
                        a = fmaf(zv[i].z, cv[m].z, a);
                        a = fmaf(zv[i].w, cv[m].w, a);
                        acc[i][m] = a;
                    }
                }
            }
        }

        // fold chunk into running best (score = ||c||^2 - 2 z.c ; ||z||^2 constant per row)
#pragma unroll
        for (int m = 0; m < 8; ++m) {
            int   c  = cb0 + tx + 64 * m;
            float cn = cnorm[c];
#pragma unroll
            for (int i = 0; i < 8; ++i) {
                float s = fmaf(-2.f, acc[i][m], cn);
                unsigned u = __float_as_uint(s);
                u = (u & 0x80000000u) ? ~u : (u | 0x80000000u);   // monotone map
                unsigned long long key = ((unsigned long long)u << 32) | (unsigned)c;
                best[i] = key < best[i] ? key : best[i];
            }
        }
    }

    // ---- wave butterfly min-reduce across the 64 lanes (codes axis) ----
#pragma unroll
    for (int i = 0; i < 8; ++i) {
        unsigned long long b = best[i];
#pragma unroll
        for (int s = 1; s < 64; s <<= 1) {
            unsigned long long o = __shfl_xor(b, s, 64);
            b = o < b ? o : b;
        }
        best[i] = b;
    }
    if (tx == 0) {
#pragma unroll
        for (int i = 0; i < 8; ++i)
            bests[ty * 8 + i] = (int)(best[i] & 0xFFFFFFFFu);
    }
    __syncthreads();

    // ---- epilogue: gather, straight-through output, loss, histogram ----
    const int r  = tid >> 3;   // 0..31
    const int lq = tid & 7;
    const int bidx = bests[r];
    const float4* crow = (const float4*)(cb + (size_t)bidx * DIM);
    const float4* zrow = (const float4*)&zs[r][0];
    float4*       orow = (float4*)(out + (size_t)(r0 + r) * DIM);
    float lsum = 0.f;
#pragma unroll
    for (int j = 0; j < 8; ++j) {
        int q = lq + j * 8;
        float4 c4 = crow[q];
        float4 z4 = zrow[q];
        float4 o;
        float dx = c4.x - z4.x; o.x = z4.x + dx; lsum = fmaf(dx, dx, lsum);
        float dy = c4.y - z4.y; o.y = z4.y + dy; lsum = fmaf(dy, dy, lsum);
        float dz = c4.z - z4.z; o.z = z4.z + dz; lsum = fmaf(dz, dz, lsum);
        float dw = c4.w - z4.w; o.w = z4.w + dw; lsum = fmaf(dw, dw, lsum);
        orow[q] = o;
    }
    if (tid < BM) atomicAdd(&counts[bests[tid]], 1);

    red[tid] = lsum;
    __syncthreads();
    for (int s = 128; s > 0; s >>= 1) {
        if (tid < s) red[tid] += red[tid + s];
        __syncthreads();
    }
    if (tid == 0) ploss[blockIdx.x] = red[0];
}

__global__ void vq_final(const float* __restrict__ ploss, const int* __restrict__ counts,
                         const int* __restrict__ flg, float* __restrict__ out2) {
    __shared__ float red[1024];
    const int t = threadIdx.x;

    // loss = (sum of partials / (N*D)) * (1 + BETA)
    float l = ploss[t] + ploss[t + 1024];
    red[t] = l;
    __syncthreads();
    for (int s = 512; s > 0; s >>= 1) {
        if (t < s) red[t] += red[t + s];
        __syncthreads();
    }
    if (t == 0) {
        float loss = (red[0] / (float)(N_ROWS * DIM)) * (1.0f + BETA);
        if (flg[0] == 0) loss = 0.f;
        out2[0] = loss;
    }
    __syncthreads();

    // perplexity
    float e = (float)counts[t] / (float)N_ROWS;
    red[t] = e * logf(e + 1e-10f);
    __syncthreads();
    for (int s = 512; s > 0; s >>= 1) {
        if (t < s) red[t] += red[t + s];
        __syncthreads();
    }
    if (t == 0) out2[1] = expf(-red[0]);
}

extern "C" void kernel_launch(void* const* d_in, const int* in_sizes, int n_in,
                              void* d_out, int out_size, void* d_ws, size_t ws_size,
                              hipStream_t stream) {
    const float* z   = (const float*)d_in[0];
    const float* cb  = (const float*)d_in[1];
    const int*   flg = (const int*)d_in[2];
    float* out = (float*)d_out;
    float* ws  = (float*)d_ws;

    float* cnorm  = ws;
    int*   counts = (int*)(ws + 1024);
    float* ploss  = ws + 2048;

    hipMemsetAsync(counts, 0, K_CODES * sizeof(int), stream);
    cnorm_kernel<<<K_CODES / 256, 256, 0, stream>>>(cb, cnorm);
    vq_main<<<NBLOCKS, 256, 0, stream>>>(z, cb, cnorm, out, counts, ploss);
    vq_final<<<1, 1024, 0, stream>>>(ploss, counts, flg, out + (size_t)N_ROWS * DIM);
}

// Round 4
// 306.098 us; speedup vs baseline: 2.3337x; 2.3337x over previous
//
#include <hip/hip_runtime.h>

// VectorQuantizer on MI355X — MFMA f16-split (scaled-lo) version.
// z: [64,1024,256] f32 -> N=65536 rows, D=256. codebook: [1024,256] f32, K=1024.
// Outputs (concat flat): z_q (16777216 f32), loss (1), perplexity (1).
//
// Precision scheme: v = hi + lo/2048, hi = f16(v), lo = f16((v-hi)*2048).
// dot(z,c) = hh + (h*l' + l*h')/2048, ll term (~1e-6) dropped.
// Round-4 fix: cross-wave (wc) argmin combine — waves 0/1 (and 2/3) share the
// same 32 z-rows but each sees only half of each 64-code chunk; their packed
// keys must be min-combined, not overwritten.

#define N_ROWS 65536
#define DIM    256
#define K_CODES 1024
#define BETA   0.001f

#define BM      64                 // rows per block
#define NBLOCKS (N_ROWS / BM)      // 1024
#define NSTAGE  32                 // 16 chunks x 2 k-halves
#define STAGE_BYTES 32768          // 64 codes x 128 k x (hi+lo) x 2B

#define LO_SCALE 2048.0f
#define LO_INV   (1.0f / 2048.0f)

// ws layout:
//   float[0,1024)    cnorm
//   int  [1024,2048) counts
//   float[2048,4096) ploss
//   byte 16384 ...   codebook f16 hi/lo image, 32 units x 32768 B = 1 MB
#define WS_CBIMG_OFF 16384
#define WS_NEED (WS_CBIMG_OFF + NSTAGE * STAGE_BYTES)

typedef _Float16 f16x8 __attribute__((ext_vector_type(8)));
typedef float f32x16 __attribute__((ext_vector_type(16)));

// ---------------- prep kernels ----------------

__global__ void cnorm_kernel(const float* __restrict__ cb, float* __restrict__ cnorm) {
    int k = blockIdx.x * blockDim.x + threadIdx.x;
    if (k >= K_CODES) return;
    const float4* row = (const float4*)(cb + (size_t)k * DIM);
    float s = 0.f;
#pragma unroll
    for (int j = 0; j < DIM / 4; ++j) {
        float4 v = row[j];
        s = fmaf(v.x, v.x, s);
        s = fmaf(v.y, v.y, s);
        s = fmaf(v.z, v.z, s);
        s = fmaf(v.w, v.w, s);
    }
    cnorm[k] = s;
}

// Codebook f32 -> f16 hi/lo(scaled), in the pre-swizzled LDS image layout.
__global__ void cb_prep(const float* __restrict__ cb, char* __restrict__ img) {
    int idx = blockIdx.x * blockDim.x + threadIdx.x;   // 0..32767
    int c   = idx >> 5;          // code 0..1023
    int g32 = idx & 31;          // granule of 8 floats
    const float4* src = (const float4*)(cb + (size_t)c * DIM + g32 * 8);
    float4 v0 = src[0], v1 = src[1];
    float vv[8] = {v0.x, v0.y, v0.z, v0.w, v1.x, v1.y, v1.z, v1.w};
    f16x8 hi, lo;
#pragma unroll
    for (int j = 0; j < 8; ++j) {
        _Float16 h = (_Float16)vv[j];
        hi[j] = h;
        lo[j] = (_Float16)((vv[j] - (float)h) * LO_SCALE);
    }
    int kh = g32 >> 4;
    int gl = g32 & 15;
    int cl = c & 63;
    int gp = gl ^ (cl & 7);
    int unit = (c >> 6) * 2 + kh;
    size_t off = (size_t)unit * STAGE_BYTES + (size_t)cl * 256 + (size_t)gp * 16;
    *(f16x8*)(img + off) = hi;
    *(f16x8*)(img + off + 16384) = lo;
}

// ---------------- MFMA main kernel ----------------

__device__ inline void stage_unit(const char* img, int u, char* ldsbase, int w, int lane) {
    const char* src = img + (size_t)u * STAGE_BYTES + w * 8192 + lane * 16;
    char* dst = ldsbase + w * 8192;
#pragma unroll
    for (int i = 0; i < 8; ++i) {
        __builtin_amdgcn_global_load_lds(
            (const __attribute__((address_space(1))) unsigned int*)(src + i * 1024),
            (__attribute__((address_space(3))) unsigned int*)(dst + i * 1024),
            16, 0, 0);
    }
}

__global__ __launch_bounds__(256, 1)
void vq_main_mfma(const float* __restrict__ z, const float* __restrict__ cb,
                  const char* __restrict__ img, const float* __restrict__ cnorm,
                  float* __restrict__ out, int* __restrict__ counts,
                  float* __restrict__ ploss) {
    __shared__ _Float16 zs_hi[BM * DIM];     // 32 KB, swizzled 16B granules
    __shared__ _Float16 zs_lo[BM * DIM];     // 32 KB (scaled lo)
    __shared__ _Float16 csb[2 * 16384];      // 64 KB
    __shared__ unsigned long long bkey2[BM][2];  // per-row keys from both wc halves
    __shared__ int bests[BM];
    __shared__ float red[256];

    const int tid  = threadIdx.x;
    const int lane = tid & 63;
    const int w    = tid >> 6;      // wave 0..3
    const int wr   = w >> 1;        // row-tile (32 rows)
    const int wc   = w & 1;         // col-tile (32 cols of the 64-code chunk)
    const int l31  = lane & 31;
    const int lh   = lane >> 5;
    const int r0   = blockIdx.x * BM;

    // ---- stage z tile: f32 -> f16 hi/lo(scaled) into swizzled LDS ----
#pragma unroll
    for (int p = 0; p < 8; ++p) {
        int i = p * 256 + tid;             // 0..2047
        int r = i >> 5, g = i & 31;        // row, granule of 8 floats
        const float4* src = (const float4*)(z + (size_t)(r0 + r) * DIM + g * 8);
        float4 v0 = src[0], v1 = src[1];
        float vv[8] = {v0.x, v0.y, v0.z, v0.w, v1.x, v1.y, v1.z, v1.w};
        f16x8 hi, lo;
#pragma unroll
        for (int j = 0; j < 8; ++j) {
            _Float16 h = (_Float16)vv[j];
            hi[j] = h;
            lo[j] = (_Float16)((vv[j] - (float)h) * LO_SCALE);
        }
        int gp = g ^ (r & 7);
        *(f16x8*)&zs_hi[r * 256 + gp * 8] = hi;
        *(f16x8*)&zs_lo[r * 256 + gp * 8] = lo;
    }
    __syncthreads();

    f32x16 acc_hh_e, acc_hh_o, acc_x_e, acc_x_o;
#pragma unroll
    for (int e = 0; e < 16; ++e) {
        acc_hh_e[e] = 0.f; acc_hh_o[e] = 0.f;
        acc_x_e[e]  = 0.f; acc_x_o[e]  = 0.f;
    }
    unsigned long long bestk[16];
#pragma unroll
    for (int e = 0; e < 16; ++e) bestk[e] = ~0ull;

    const int zrow = wr * 32 + l31;
    const _Float16* zh_row = zs_hi + zrow * 256;
    const _Float16* zl_row = zs_lo + zrow * 256;
    const int zsw = zrow & 7;
    const int crow = wc * 32 + l31;                // code row within chunk
    const int csw = crow & 7;

    // prologue: stage unit 0 into buf 0
    stage_unit(img, 0, (char*)csb, w, lane);

#pragma unroll 1
    for (int u = 0; u < NSTAGE; ++u) {
        const int b = u & 1;
        asm volatile("" ::: "memory");
        __builtin_amdgcn_s_barrier();              // close compute(u-1)
        asm volatile("" ::: "memory");
        if (u + 1 < NSTAGE) {
            stage_unit(img, u + 1, (char*)csb + (b ^ 1) * 32768, w, lane);
            asm volatile("s_waitcnt vmcnt(8)" ::: "memory");
        } else {
            asm volatile("s_waitcnt vmcnt(0)" ::: "memory");
        }
        __builtin_amdgcn_s_barrier();              // stage(u) visible
        asm volatile("" ::: "memory");

        const int kh = u & 1, chunk = u >> 1;
        const _Float16* ch_row = csb + b * 16384 + crow * 128;
        const _Float16* cl_row = ch_row + 8192;

#pragma unroll
        for (int ks = 0; ks < 8; ++ks) {
            int ga = (kh * 16 + ks * 2 + lh) ^ zsw;
            int gb = (ks * 2 + lh) ^ csw;
            f16x8 ah = *(const f16x8*)(zh_row + ga * 8);
            f16x8 al = *(const f16x8*)(zl_row + ga * 8);
            f16x8 bh = *(const f16x8*)(ch_row + gb * 8);
            f16x8 bl = *(const f16x8*)(cl_row + gb * 8);
            f32x16& ahh = (ks & 1) ? acc_hh_o : acc_hh_e;
            f32x16& ax  = (ks & 1) ? acc_x_o  : acc_x_e;
            ahh = __builtin_amdgcn_mfma_f32_32x32x16_f16(ah, bh, ahh, 0, 0, 0);
            ax  = __builtin_amdgcn_mfma_f32_32x32x16_f16(ah, bl, ax, 0, 0, 0);
            ax  = __builtin_amdgcn_mfma_f32_32x32x16_f16(al, bh, ax, 0, 0, 0);
        }

        if (kh == 1) {
            // fold chunk: score = ||c||^2 - 2 z.c  (||z||^2 row-constant)
            int col = chunk * 64 + wc * 32 + l31;
            float cn = cnorm[col];
#pragma unroll
            for (int rg = 0; rg < 16; ++rg) {
                float dot = fmaf(acc_x_e[rg] + acc_x_o[rg], LO_INV,
                                 acc_hh_e[rg] + acc_hh_o[rg]);
                float s = fmaf(-2.0f, dot, cn);
                unsigned uu = __float_as_uint(s);
                uu = (uu & 0x80000000u) ? ~uu : (uu | 0x80000000u);
                unsigned long long key = ((unsigned long long)uu << 32) | (unsigned)col;
                bestk[rg] = key < bestk[rg] ? key : bestk[rg];
            }
#pragma unroll
            for (int e = 0; e < 16; ++e) {
                acc_hh_e[e] = 0.f; acc_hh_o[e] = 0.f;
                acc_x_e[e]  = 0.f; acc_x_o[e]  = 0.f;
            }
        }
    }

    // ---- reduce best over the 32 lanes of each half (cols axis) ----
#pragma unroll
    for (int rg = 0; rg < 16; ++rg) {
        unsigned long long bk = bestk[rg];
#pragma unroll
        for (int s = 1; s < 32; s <<= 1) {
            unsigned long long o = __shfl_xor(bk, s, 64);
            bk = o < bk ? o : bk;
        }
        bestk[rg] = bk;
    }
    if (l31 == 0) {
#pragma unroll
        for (int rg = 0; rg < 16; ++rg) {
            int rl = (rg & 3) + 8 * (rg >> 2) + 4 * lh;   // C/D row mapping (m74/m101)
            bkey2[wr * 32 + rl][wc] = bestk[rg];
        }
    }
    __syncthreads();
    if (tid < BM) {
        unsigned long long a = bkey2[tid][0];
        unsigned long long b2 = bkey2[tid][1];
        bests[tid] = (int)((a < b2 ? a : b2) & 0xffffffffu);
    }
    __syncthreads();

    // ---- epilogue: gather, straight-through output, loss, histogram ----
    const int r = tid >> 2;        // row 0..63
    const int q = tid & 3;         // quarter of the row
    const int bidx = bests[r];
    const float* crow_g = cb + (size_t)bidx * DIM;
    float* orow = out + (size_t)(r0 + r) * DIM;
    float lsum = 0.f;
#pragma unroll
    for (int j = 0; j < 8; ++j) {
        int g = q * 8 + j;
        int gp = g ^ (r & 7);
        f16x8 h = *(const f16x8*)&zs_hi[r * 256 + gp * 8];
        f16x8 l = *(const f16x8*)&zs_lo[r * 256 + gp * 8];
        float4 c0 = *(const float4*)(crow_g + g * 8);
        float4 c1 = *(const float4*)(crow_g + g * 8 + 4);
        float cv[8] = {c0.x, c0.y, c0.z, c0.w, c1.x, c1.y, c1.z, c1.w};
        float ov[8];
#pragma unroll
        for (int e = 0; e < 8; ++e) {
            float zz = fmaf((float)l[e], LO_INV, (float)h[e]);
            float d = cv[e] - zz;
            ov[e] = zz + d;
            lsum = fmaf(d, d, lsum);
        }
        float4 o0 = {ov[0], ov[1], ov[2], ov[3]};
        float4 o1 = {ov[4], ov[5], ov[6], ov[7]};
        *(float4*)(orow + g * 8) = o0;
        *(float4*)(orow + g * 8 + 4) = o1;
    }
    if (tid < BM) atomicAdd(&counts[bests[tid]], 1);

    red[tid] = lsum;
    __syncthreads();
    for (int s = 128; s > 0; s >>= 1) {
        if (tid < s) red[tid] += red[tid + s];
        __syncthreads();
    }
    if (tid == 0) ploss[blockIdx.x] = red[0];
}

// ---------------- fallback fp32 kernel (round-1, known-good) ----------------

#define FBM     32
#define FCHUNK  512
#define FDSTAGE 16
#define FCS_PAD 20
#define FNBLOCKS (N_ROWS / FBM)   // 2048

__global__ __launch_bounds__(256, 2)
void vq_main_fp32(const float* __restrict__ z, const float* __restrict__ cb,
                  const float* __restrict__ cnorm, float* __restrict__ out,
                  int* __restrict__ counts, float* __restrict__ ploss) {
    __shared__ float zs[FBM][DIM];
    __shared__ float cs[FCHUNK][FCS_PAD];
    __shared__ int   bests[FBM];
    __shared__ float red[256];

    const int tid = threadIdx.x;
    const int tx  = tid & 63;
    const int ty  = tid >> 6;
    const int r0  = blockIdx.x * FBM;

    {
        const float4* zg  = (const float4*)(z + (size_t)r0 * DIM);
        float4*       zsv = (float4*)&zs[0][0];
#pragma unroll
        for (int j = 0; j < (FBM * DIM / 4) / 256; ++j)
            zsv[tid + 256 * j] = zg[tid + 256 * j];
    }

    unsigned long long best[8];
#pragma unroll
    for (int i = 0; i < 8; ++i) best[i] = ~0ull;

    for (int cb0 = 0; cb0 < K_CODES; cb0 += FCHUNK) {
        float acc[8][8];
#pragma unroll
        for (int i = 0; i < 8; ++i)
#pragma unroll
            for (int m = 0; m < 8; ++m) acc[i][m] = 0.f;

        for (int sd = 0; sd < DIM / FDSTAGE; ++sd) {
            __syncthreads();
#pragma unroll
            for (int j = 0; j < 8; ++j) {
                int f4i = tid + 256 * j;
                int c   = f4i >> 2;
                int qq  = f4i & 3;
                float4 v = *(const float4*)(cb + (size_t)(cb0 + c) * DIM + sd * FDSTAGE + qq * 4);
                *(float4*)&cs[c][qq * 4] = v;
            }
            __syncthreads();

#pragma unroll
            for (int dd4 = 0; dd4 < FDSTAGE / 4; ++dd4) {
                float4 zv[8], cv[8];
#pragma unroll
                for (int i = 0; i < 8; ++i)
                    zv[i] = *(const float4*)&zs[ty * 8 + i][sd * FDSTAGE + dd4 * 4];
#pragma unroll
                for (int m = 0; m < 8; ++m)
                    cv[m] = *(const float4*)&cs[tx + 64 * m][dd4 * 4];
#pragma unroll
                for (int i = 0; i < 8; ++i)
#pragma unroll
                    for (int m = 0; m < 8; ++m) {
                        float a = acc[i][m];
                        a = fmaf(zv[i].x, cv[m].x, a);
                        a = fmaf(zv[i].y, cv[m].y, a);
                        a = fmaf(zv[i].z, cv[m].z, a);
                        a = fmaf(zv[i].w, cv[m].w, a);
                        acc[i][m] = a;
                    }
            }
        }

#pragma unroll
        for (int m = 0; m < 8; ++m) {
            int   c  = cb0 + tx + 64 * m;
            float cn = cnorm[c];
#pragma unroll
            for (int i = 0; i < 8; ++i) {
                float s = fmaf(-2.f, acc[i][m], cn);
                unsigned u = __float_as_uint(s);
                u = (u & 0x80000000u) ? ~u : (u | 0x80000000u);
                unsigned long long key = ((unsigned long long)u << 32) | (unsigned)c;
                best[i] = key < best[i] ? key : best[i];
            }
        }
    }

#pragma unroll
    for (int i = 0; i < 8; ++i) {
        unsigned long long b = best[i];
#pragma unroll
        for (int s = 1; s < 64; s <<= 1) {
            unsigned long long o = __shfl_xor(b, s, 64);
            b = o < b ? o : b;
        }
        best[i] = b;
    }
    if (tx == 0)
#pragma unroll
        for (int i = 0; i < 8; ++i)
            bests[ty * 8 + i] = (int)(best[i] & 0xFFFFFFFFu);
    __syncthreads();

    const int r  = tid >> 3;
    const int lq = tid & 7;
    const int bidx = bests[r];
    const float4* crow = (const float4*)(cb + (size_t)bidx * DIM);
    const float4* zrow = (const float4*)&zs[r][0];
    float4*       orow = (float4*)(out + (size_t)(r0 + r) * DIM);
    float lsum = 0.f;
#pragma unroll
    for (int j = 0; j < 8; ++j) {
        int qg = lq + j * 8;
        float4 c4 = crow[qg];
        float4 z4 = zrow[qg];
        float4 o;
        float dx = c4.x - z4.x; o.x = z4.x + dx; lsum = fmaf(dx, dx, lsum);
        float dy = c4.y - z4.y; o.y = z4.y + dy; lsum = fmaf(dy, dy, lsum);
        float dz = c4.z - z4.z; o.z = z4.z + dz; lsum = fmaf(dz, dz, lsum);
        float dw = c4.w - z4.w; o.w = z4.w + dw; lsum = fmaf(dw, dw, lsum);
        orow[qg] = o;
    }
    if (tid < FBM) atomicAdd(&counts[bests[tid]], 1);

    red[tid] = lsum;
    __syncthreads();
    for (int s = 128; s > 0; s >>= 1) {
        if (tid < s) red[tid] += red[tid + s];
        __syncthreads();
    }
    if (tid == 0) ploss[blockIdx.x] = red[0];
}

// ---------------- finalize ----------------

__global__ void vq_final(const float* __restrict__ ploss, const int* __restrict__ counts,
                         const int* __restrict__ flg, float* __restrict__ out2, int np) {
    __shared__ float red[1024];
    const int t = threadIdx.x;

    float l = 0.f;
    for (int i = t; i < np; i += 1024) l += ploss[i];
    red[t] = l;
    __syncthreads();
    for (int s = 512; s > 0; s >>= 1) {
        if (t < s) red[t] += red[t + s];
        __syncthreads();
    }
    if (t == 0) {
        float loss = (red[0] / (float)((size_t)N_ROWS * DIM)) * (1.0f + BETA);
        if (flg[0] == 0) loss = 0.f;
        out2[0] = loss;
    }
    __syncthreads();

    float e = (float)counts[t] / (float)N_ROWS;
    red[t] = e * logf(e + 1e-10f);
    __syncthreads();
    for (int s = 512; s > 0; s >>= 1) {
        if (t < s) red[t] += red[t + s];
        __syncthreads();
    }
    if (t == 0) out2[1] = expf(-red[0]);
}

extern "C" void kernel_launch(void* const* d_in, const int* in_sizes, int n_in,
                              void* d_out, int out_size, void* d_ws, size_t ws_size,
                              hipStream_t stream) {
    const float* z   = (const float*)d_in[0];
    const float* cb  = (const float*)d_in[1];
    const int*   flg = (const int*)d_in[2];
    float* out = (float*)d_out;
    float* ws  = (float*)d_ws;

    float* cnorm  = ws;
    int*   counts = (int*)(ws + 1024);
    float* ploss  = ws + 2048;
    char*  cbimg  = (char*)d_ws + WS_CBIMG_OFF;

    hipMemsetAsync(counts, 0, K_CODES * sizeof(int), stream);
    cnorm_kernel<<<K_CODES / 256, 256, 0, stream>>>(cb, cnorm);

    if (ws_size >= (size_t)WS_NEED) {
        cb_prep<<<128, 256, 0, stream>>>(cb, cbimg);
        vq_main_mfma<<<NBLOCKS, 256, 0, stream>>>(z, cb, cbimg, cnorm, out, counts, ploss);
        vq_final<<<1, 1024, 0, stream>>>(ploss, counts, flg, out + (size_t)N_ROWS * DIM, NBLOCKS);
    } else {
        vq_main_fp32<<<FNBLOCKS, 256, 0, stream>>>(z, cb, cnorm, out, counts, ploss);
        vq_final<<<1, 1024, 0, stream>>>(ploss, counts, flg, out + (size_t)N_ROWS * DIM, FNBLOCKS);
    }
}

// Round 5
// 182.099 us; speedup vs baseline: 3.9228x; 1.6809x over previous
//
#include <hip/hip_runtime.h>

// VectorQuantizer on MI355X — MFMA f16-split, z-in-registers version.
// z: [64,1024,256] f32 -> N=65536 rows, D=256. codebook: [1024,256] f32, K=1024.
// Outputs (concat flat): z_q (16777216 f32), loss (1), perplexity (1).
//
// Precision: v = hi + lo/2048 (f16 each); dot = hh + (h*l' + l*h')/2048.
// Round-5: z frags in VGPRs (halves LDS reads), BM=128 / 8 waves (2 waves/SIMD),
// coalesced epilogue writes.

#define N_ROWS 65536
#define DIM    256
#define K_CODES 1024
#define BETA   0.001f

#define BM      128                // rows per block
#define NBLOCKS (N_ROWS / BM)      // 512
#define NTHREADS 512
#define STAGE_BYTES 32768          // 64 codes x 128 k x (hi+lo) x 2B
#define NSTAGE  32

#define LO_SCALE 2048.0f
#define LO_INV   (1.0f / 2048.0f)

// ws layout:
//   float[0,1024)    cnorm
//   int  [1024,2048) counts
//   float[2048,4096) ploss
//   byte 16384 ...   codebook f16 hi/lo image, 32 units x 32768 B = 1 MB
#define WS_CBIMG_OFF 16384
#define WS_NEED (WS_CBIMG_OFF + NSTAGE * STAGE_BYTES)

typedef _Float16 f16x8 __attribute__((ext_vector_type(8)));
typedef float f32x16 __attribute__((ext_vector_type(16)));

// ---------------- prep kernels ----------------

__global__ void cnorm_kernel(const float* __restrict__ cb, float* __restrict__ cnorm) {
    int k = blockIdx.x * blockDim.x + threadIdx.x;
    if (k >= K_CODES) return;
    const float4* row = (const float4*)(cb + (size_t)k * DIM);
    float s = 0.f;
#pragma unroll
    for (int j = 0; j < DIM / 4; ++j) {
        float4 v = row[j];
        s = fmaf(v.x, v.x, s);
        s = fmaf(v.y, v.y, s);
        s = fmaf(v.z, v.z, s);
        s = fmaf(v.w, v.w, s);
    }
    cnorm[k] = s;
}

// Codebook f32 -> f16 hi/lo(scaled), pre-swizzled LDS image layout.
// Unit u = chunk*2 + kh, 32768 B: hi at byte = c_local*256 + (g^(c_local&7))*16,
// lo at +16384. (g = k_local/8 within the 128-k half.)
__global__ void cb_prep(const float* __restrict__ cb, char* __restrict__ img) {
    int idx = blockIdx.x * blockDim.x + threadIdx.x;   // 0..32767
    int c   = idx >> 5;          // code 0..1023
    int g32 = idx & 31;          // granule of 8 floats
    const float4* src = (const float4*)(cb + (size_t)c * DIM + g32 * 8);
    float4 v0 = src[0], v1 = src[1];
    float vv[8] = {v0.x, v0.y, v0.z, v0.w, v1.x, v1.y, v1.z, v1.w};
    f16x8 hi, lo;
#pragma unroll
    for (int j = 0; j < 8; ++j) {
        _Float16 h = (_Float16)vv[j];
        hi[j] = h;
        lo[j] = (_Float16)((vv[j] - (float)h) * LO_SCALE);
    }
    int kh = g32 >> 4;
    int gl = g32 & 15;
    int cl = c & 63;
    int gp = gl ^ (cl & 7);
    int unit = (c >> 6) * 2 + kh;
    size_t off = (size_t)unit * STAGE_BYTES + (size_t)cl * 256 + (size_t)gp * 16;
    *(f16x8*)(img + off) = hi;
    *(f16x8*)(img + off + 16384) = lo;
}

// ---------------- MFMA main kernel ----------------

__device__ inline void stage_unit(const char* img, int u, char* ldsbase, int tid) {
#pragma unroll
    for (int i = 0; i < 4; ++i) {
        __builtin_amdgcn_global_load_lds(
            (const __attribute__((address_space(1))) unsigned int*)
                (img + (size_t)u * STAGE_BYTES + i * 8192 + tid * 16),
            (__attribute__((address_space(3))) unsigned int*)
                (ldsbase + i * 8192 + tid * 16),
            16, 0, 0);
    }
}

#define COMPUTE_HALF(KH, BUF)                                                        \
    {                                                                                \
        const _Float16* ch_row = csb + (BUF) * 16384 + crow * 128;                   \
        const _Float16* cl_row = ch_row + 8192;                                      \
        _Pragma("unroll")                                                            \
        for (int ks = 0; ks < 8; ++ks) {                                             \
            int gb = (ks * 2 + lh) ^ csw;                                            \
            f16x8 bh = *(const f16x8*)(ch_row + gb * 8);                             \
            f16x8 bl = *(const f16x8*)(cl_row + gb * 8);                             \
            f16x8 ah = zh[(KH) * 8 + ks];                                            \
            f16x8 al = zl[(KH) * 8 + ks];                                            \
            acc_hh = __builtin_amdgcn_mfma_f32_32x32x16_f16(ah, bh, acc_hh, 0, 0, 0);\
            f32x16& ax = (ks & 1) ? acc_xo : acc_xe;                                 \
            ax = __builtin_amdgcn_mfma_f32_32x32x16_f16(ah, bl, ax, 0, 0, 0);        \
            ax = __builtin_amdgcn_mfma_f32_32x32x16_f16(al, bh, ax, 0, 0, 0);        \
        }                                                                            \
    }

__global__ __launch_bounds__(NTHREADS, 2)
void vq_main_mfma(const float* __restrict__ z, const float* __restrict__ cb,
                  const char* __restrict__ img, const float* __restrict__ cnorm,
                  float* __restrict__ out, int* __restrict__ counts,
                  float* __restrict__ ploss) {
    __shared__ _Float16 csb[2 * 16384];          // 64 KB double-buffered B
    __shared__ unsigned long long bkey2[BM][2];  // 2 KB
    __shared__ int bests[BM];
    __shared__ float red[NTHREADS];

    const int tid  = threadIdx.x;
    const int lane = tid & 63;
    const int w    = tid >> 6;      // wave 0..7
    const int wr   = w >> 1;        // row-tile 0..3 (32 rows each)
    const int wc   = w & 1;         // col-half of 64-code chunk
    const int l31  = lane & 31;
    const int lh   = lane >> 5;
    const int r0   = blockIdx.x * BM;

    // issue first staging unit early
    stage_unit(img, 0, (char*)csb, tid);

    // ---- z fragments -> registers (f16 hi/lo, MFMA A layout) ----
    const int zrow = wr * 32 + l31;
    f16x8 zh[16], zl[16];
    {
        const float* zr = z + (size_t)(r0 + zrow) * DIM;
#pragma unroll
        for (int gi = 0; gi < 16; ++gi) {
            int g = gi * 2 + lh;                 // granule parity = lh
            float4 v0 = *(const float4*)(zr + g * 8);
            float4 v1 = *(const float4*)(zr + g * 8 + 4);
            float vv[8] = {v0.x, v0.y, v0.z, v0.w, v1.x, v1.y, v1.z, v1.w};
            f16x8 hi, lo;
#pragma unroll
            for (int j = 0; j < 8; ++j) {
                _Float16 h = (_Float16)vv[j];
                hi[j] = h;
                lo[j] = (_Float16)((vv[j] - (float)h) * LO_SCALE);
            }
            zh[gi] = hi;
            zl[gi] = lo;
        }
    }

    f32x16 acc_hh, acc_xe, acc_xo;
#pragma unroll
    for (int e = 0; e < 16; ++e) { acc_hh[e] = 0.f; acc_xe[e] = 0.f; acc_xo[e] = 0.f; }
    unsigned long long bestk[16];
#pragma unroll
    for (int e = 0; e < 16; ++e) bestk[e] = ~0ull;

    const int crow = wc * 32 + l31;              // code row within 64-chunk
    const int csw  = crow & 7;

#pragma unroll 1
    for (int chunk = 0; chunk < 16; ++chunk) {
        // ---- u = 2*chunk (kh=0, buf0) ----
        asm volatile("" ::: "memory");
        __builtin_amdgcn_s_barrier();            // close previous compute on buf1
        asm volatile("" ::: "memory");
        stage_unit(img, 2 * chunk + 1, (char*)csb + 32768, tid);
        asm volatile("s_waitcnt vmcnt(4)" ::: "memory");   // stage(2*chunk) done
        __builtin_amdgcn_s_barrier();
        asm volatile("" ::: "memory");
        __builtin_amdgcn_s_setprio(1);
        COMPUTE_HALF(0, 0)
        __builtin_amdgcn_s_setprio(0);

        // ---- u = 2*chunk+1 (kh=1, buf1) ----
        asm volatile("" ::: "memory");
        __builtin_amdgcn_s_barrier();            // close compute on buf0
        asm volatile("" ::: "memory");
        if (chunk + 1 < 16) {
            stage_unit(img, 2 * chunk + 2, (char*)csb, tid);
            asm volatile("s_waitcnt vmcnt(4)" ::: "memory");
        } else {
            asm volatile("s_waitcnt vmcnt(0)" ::: "memory");
        }
        __builtin_amdgcn_s_barrier();
        asm volatile("" ::: "memory");
        __builtin_amdgcn_s_setprio(1);
        COMPUTE_HALF(1, 1)
        __builtin_amdgcn_s_setprio(0);

        // ---- fold chunk: score = ||c||^2 - 2 z.c ----
        {
            int col = chunk * 64 + wc * 32 + l31;
            float cn = cnorm[col];
#pragma unroll
            for (int rg = 0; rg < 16; ++rg) {
                float dot = fmaf(acc_xe[rg] + acc_xo[rg], LO_INV, acc_hh[rg]);
                float s = fmaf(-2.0f, dot, cn);
                unsigned uu = __float_as_uint(s);
                uu = (uu & 0x80000000u) ? ~uu : (uu | 0x80000000u);
                unsigned long long key = ((unsigned long long)uu << 32) | (unsigned)col;
                bestk[rg] = key < bestk[rg] ? key : bestk[rg];
            }
#pragma unroll
            for (int e = 0; e < 16; ++e) { acc_hh[e] = 0.f; acc_xe[e] = 0.f; acc_xo[e] = 0.f; }
        }
    }

    // ---- reduce best over the 32 lanes of each half (codes axis) ----
#pragma unroll
    for (int rg = 0; rg < 16; ++rg) {
        unsigned long long bk = bestk[rg];
#pragma unroll
        for (int s = 1; s < 32; s <<= 1) {
            unsigned long long o = __shfl_xor(bk, s, 64);
            bk = o < bk ? o : bk;
        }
        bestk[rg] = bk;
    }
    if (l31 == 0) {
#pragma unroll
        for (int rg = 0; rg < 16; ++rg) {
            int rl = (rg & 3) + 8 * (rg >> 2) + 4 * lh;   // C/D row mapping (m74/m101)
            bkey2[wr * 32 + rl][wc] = bestk[rg];
        }
    }
    __syncthreads();
    if (tid < BM) {
        unsigned long long a = bkey2[tid][0];
        unsigned long long b2 = bkey2[tid][1];
        bests[tid] = (int)((a < b2 ? a : b2) & 0xffffffffu);
    }
    __syncthreads();

    // ---- epilogue: gather, straight-through output, loss, histogram ----
    const int r = tid >> 2;        // row 0..127
    const int q = tid & 3;
    const int bidx = bests[r];
    const float* crow_g = cb + (size_t)bidx * DIM;
    const float* zrow_g = z + (size_t)(r0 + r) * DIM;
    float* orow = out + (size_t)(r0 + r) * DIM;
    float lsum = 0.f;
#pragma unroll
    for (int j = 0; j < 16; ++j) {
        int g4 = j * 4 + q;                     // float4 index; 4 lanes -> 64B line
        float4 c4 = *(const float4*)(crow_g + g4 * 4);
        float4 z4 = *(const float4*)(zrow_g + g4 * 4);
        float4 o;
        float dx = c4.x - z4.x; o.x = z4.x + dx; lsum = fmaf(dx, dx, lsum);
        float dy = c4.y - z4.y; o.y = z4.y + dy; lsum = fmaf(dy, dy, lsum);
        float dz = c4.z - z4.z; o.z = z4.z + dz; lsum = fmaf(dz, dz, lsum);
        float dw = c4.w - z4.w; o.w = z4.w + dw; lsum = fmaf(dw, dw, lsum);
        *(float4*)(orow + g4 * 4) = o;
    }
    if (tid < BM) atomicAdd(&counts[bests[tid]], 1);

    red[tid] = lsum;
    __syncthreads();
    for (int s = NTHREADS / 2; s > 0; s >>= 1) {
        if (tid < s) red[tid] += red[tid + s];
        __syncthreads();
    }
    if (tid == 0) ploss[blockIdx.x] = red[0];
}

// ---------------- fallback fp32 kernel (round-1, known-good) ----------------

#define FBM     32
#define FCHUNK  512
#define FDSTAGE 16
#define FCS_PAD 20
#define FNBLOCKS (N_ROWS / FBM)   // 2048

__global__ __launch_bounds__(256, 2)
void vq_main_fp32(const float* __restrict__ z, const float* __restrict__ cb,
                  const float* __restrict__ cnorm, float* __restrict__ out,
                  int* __restrict__ counts, float* __restrict__ ploss) {
    __shared__ float zs[FBM][DIM];
    __shared__ float cs[FCHUNK][FCS_PAD];
    __shared__ int   bests[FBM];
    __shared__ float red[256];

    const int tid = threadIdx.x;
    const int tx  = tid & 63;
    const int ty  = tid >> 6;
    const int r0  = blockIdx.x * FBM;

    {
        const float4* zg  = (const float4*)(z + (size_t)r0 * DIM);
        float4*       zsv = (float4*)&zs[0][0];
#pragma unroll
        for (int j = 0; j < (FBM * DIM / 4) / 256; ++j)
            zsv[tid + 256 * j] = zg[tid + 256 * j];
    }

    unsigned long long best[8];
#pragma unroll
    for (int i = 0; i < 8; ++i) best[i] = ~0ull;

    for (int cb0 = 0; cb0 < K_CODES; cb0 += FCHUNK) {
        float acc[8][8];
#pragma unroll
        for (int i = 0; i < 8; ++i)
#pragma unroll
            for (int m = 0; m < 8; ++m) acc[i][m] = 0.f;

        for (int sd = 0; sd < DIM / FDSTAGE; ++sd) {
            __syncthreads();
#pragma unroll
            for (int j = 0; j < 8; ++j) {
                int f4i = tid + 256 * j;
                int c   = f4i >> 2;
                int qq  = f4i & 3;
                float4 v = *(const float4*)(cb + (size_t)(cb0 + c) * DIM + sd * FDSTAGE + qq * 4);
                *(float4*)&cs[c][qq * 4] = v;
            }
            __syncthreads();

#pragma unroll
            for (int dd4 = 0; dd4 < FDSTAGE / 4; ++dd4) {
                float4 zv[8], cv[8];
#pragma unroll
                for (int i = 0; i < 8; ++i)
                    zv[i] = *(const float4*)&zs[ty * 8 + i][sd * FDSTAGE + dd4 * 4];
#pragma unroll
                for (int m = 0; m < 8; ++m)
                    cv[m] = *(const float4*)&cs[tx + 64 * m][dd4 * 4];
#pragma unroll
                for (int i = 0; i < 8; ++i)
#pragma unroll
                    for (int m = 0; m < 8; ++m) {
                        float a = acc[i][m];
                        a = fmaf(zv[i].x, cv[m].x, a);
                        a = fmaf(zv[i].y, cv[m].y, a);
                        a = fmaf(zv[i].z, cv[m].z, a);
                        a = fmaf(zv[i].w, cv[m].w, a);
                        acc[i][m] = a;
                    }
            }
        }

#pragma unroll
        for (int m = 0; m < 8; ++m) {
            int   c  = cb0 + tx + 64 * m;
            float cn = cnorm[c];
#pragma unroll
            for (int i = 0; i < 8; ++i) {
                float s = fmaf(-2.f, acc[i][m], cn);
                unsigned u = __float_as_uint(s);
                u = (u & 0x80000000u) ? ~u : (u | 0x80000000u);
                unsigned long long key = ((unsigned long long)u << 32) | (unsigned)c;
                best[i] = key < best[i] ? key : best[i];
            }
        }
    }

#pragma unroll
    for (int i = 0; i < 8; ++i) {
        unsigned long long b = best[i];
#pragma unroll
        for (int s = 1; s < 64; s <<= 1) {
            unsigned long long o = __shfl_xor(b, s, 64);
            b = o < b ? o : b;
        }
        best[i] = b;
    }
    if (tx == 0)
#pragma unroll
        for (int i = 0; i < 8; ++i)
            bests[ty * 8 + i] = (int)(best[i] & 0xFFFFFFFFu);
    __syncthreads();

    const int r  = tid >> 3;
    const int lq = tid & 7;
    const int bidx = bests[r];
    const float4* crow = (const float4*)(cb + (size_t)bidx * DIM);
    const float4* zrow = (const float4*)&zs[r][0];
    float4*       orow = (float4*)(out + (size_t)(r0 + r) * DIM);
    float lsum = 0.f;
#pragma unroll
    for (int j = 0; j < 8; ++j) {
        int qg = lq + j * 8;
        float4 c4 = crow[qg];
        float4 z4 = zrow[qg];
        float4 o;
        float dx = c4.x - z4.x; o.x = z4.x + dx; lsum = fmaf(dx, dx, lsum);
        float dy = c4.y - z4.y; o.y = z4.y + dy; lsum = fmaf(dy, dy, lsum);
        float dz = c4.z - z4.z; o.z = z4.z + dz; lsum = fmaf(dz, dz, lsum);
        float dw = c4.w - z4.w; o.w = z4.w + dw; lsum = fmaf(dw, dw, lsum);
        orow[qg] = o;
    }
    if (tid < FBM) atomicAdd(&counts[bests[tid]], 1);

    red[tid] = lsum;
    __syncthreads();
    for (int s = 128; s > 0; s >>= 1) {
        if (tid < s) red[tid] += red[tid + s];
        __syncthreads();
    }
    if (tid == 0) ploss[blockIdx.x] = red[0];
}

// ---------------- finalize ----------------

__global__ void vq_final(const float* __restrict__ ploss, const int* __restrict__ counts,
                         const int* __restrict__ flg, float* __restrict__ out2, int np) {
    __shared__ float red[1024];
    const int t = threadIdx.x;

    float l = 0.f;
    for (int i = t; i < np; i += 1024) l += ploss[i];
    red[t] = l;
    __syncthreads();
    for (int s = 512; s > 0; s >>= 1) {
        if (t < s) red[t] += red[t + s];
        __syncthreads();
    }
    if (t == 0) {
        float loss = (red[0] / (float)((size_t)N_ROWS * DIM)) * (1.0f + BETA);
        if (flg[0] == 0) loss = 0.f;
        out2[0] = loss;
    }
    __syncthreads();

    float e = (float)counts[t] / (float)N_ROWS;
    red[t] = e * logf(e + 1e-10f);
    __syncthreads();
    for (int s = 512; s > 0; s >>= 1) {
        if (t < s) red[t] += red[t + s];
        __syncthreads();
    }
    if (t == 0) out2[1] = expf(-red[0]);
}

extern "C" void kernel_launch(void* const* d_in, const int* in_sizes, int n_in,
                              void* d_out, int out_size, void* d_ws, size_t ws_size,
                              hipStream_t stream) {
    const float* z   = (const float*)d_in[0];
    const float* cb  = (const float*)d_in[1];
    const int*   flg = (const int*)d_in[2];
    float* out = (float*)d_out;
    float* ws  = (float*)d_ws;

    float* cnorm  = ws;
    int*   counts = (int*)(ws + 1024);
    float* ploss  = ws + 2048;
    char*  cbimg  = (char*)d_ws + WS_CBIMG_OFF;

    hipMemsetAsync(counts, 0, K_CODES * sizeof(int), stream);
    cnorm_kernel<<<K_CODES / 256, 256, 0, stream>>>(cb, cnorm);

    if (ws_size >= (size_t)WS_NEED) {
        cb_prep<<<128, 256, 0, stream>>>(cb, cbimg);
        vq_main_mfma<<<NBLOCKS, NTHREADS, 0, stream>>>(z, cb, cbimg, cnorm, out, counts, ploss);
        vq_final<<<1, 1024, 0, stream>>>(ploss, counts, flg, out + (size_t)N_ROWS * DIM, NBLOCKS);
    } else {
        vq_main_fp32<<<FNBLOCKS, 256, 0, stream>>>(z, cb, cnorm, out, counts, ploss);
        vq_final<<<1, 1024, 0, stream>>>(ploss, counts, flg, out + (size_t)N_ROWS * DIM, FNBLOCKS);
    }
}